// Round 1
// baseline (1737.691 us; speedup 1.0000x reference)
//
#include <hip/hip_runtime.h>
#include <math.h>

#define NCLS 31
#define B 4096
#define D 512
#define N 8192
#define BT 128
#define BK 32

// ws float layout
#define WS_SUMSQ 0    // atomic: sum of row norms^2
#define WS_ACC   1    // atomic: loss accumulator
#define WS_NB    2    // 5 floats: -1/(bw*2^k)
#define WS_SL    7    // scale * lamb
#define WS_SVAL  8    // 32 floats: per-class source value m_c/count_c
#define WS_TVAL  40   // 32 floats: per-class target value -m_c/colsum_c
#define WS_COL   72   // 512 floats: column sums of X (atomic)
#define WS_SQ    1024 // 8192 floats: per-row squared norms

__global__ void k_sq(const float* __restrict__ src, const float* __restrict__ tgt,
                     float* __restrict__ wsf) {
  int row = blockIdx.x * 4 + (threadIdx.x >> 6);
  int lane = threadIdx.x & 63;
  const float* p = (row < B) ? src + (size_t)row * D : tgt + (size_t)(row - B) * D;
  const float4* p4 = (const float4*)p;
  float4 a = p4[lane], b = p4[lane + 64];
  float s = a.x*a.x + a.y*a.y + a.z*a.z + a.w*a.w
          + b.x*b.x + b.y*b.y + b.z*b.z + b.w*b.w;
  #pragma unroll
  for (int off = 32; off; off >>= 1) s += __shfl_down(s, off);
  if (lane == 0) {
    wsf[WS_SQ + row] = s;
    atomicAdd(&wsf[WS_SUMSQ], s);
  }
}

__global__ void k_colsum(const float* __restrict__ src, const float* __restrict__ tgt,
                         float* __restrict__ wsf) {
  int d = blockIdx.x * 256 + threadIdx.x;
  int r0 = blockIdx.y * 256;  // chunks of 256 rows never straddle the src/tgt boundary
  const float* base = (r0 < B) ? src + (size_t)r0 * D : tgt + (size_t)(r0 - B) * D;
  float s = 0.f;
  for (int r = 0; r < 256; r++) s += base[(size_t)r * D + d];
  atomicAdd(&wsf[WS_COL + d], s);
}

__global__ void k_classes(const int* __restrict__ label, const float* __restrict__ logits,
                          const int* __restrict__ iter_p, float* __restrict__ wsf) {
  __shared__ int cnt[NCLS];
  __shared__ float csum[NCLS];
  __shared__ unsigned presT;
  int tid = threadIdx.x;
  if (tid < NCLS) { cnt[tid] = 0; csum[tid] = 0.f; }
  if (tid == 0) presT = 0u;
  __syncthreads();
  float acc[NCLS];
  #pragma unroll
  for (int c = 0; c < NCLS; c++) acc[c] = 0.f;
  for (int r = tid; r < B; r += 256) {
    atomicAdd(&cnt[label[r]], 1);
    const float* lp = logits + (size_t)r * NCLS;
    float mx = -1e30f; int am = 0;
    #pragma unroll
    for (int c = 0; c < NCLS; c++) {
      float v = lp[c];
      acc[c] += v;
      if (v > mx) { mx = v; am = c; }  // strict > keeps first occurrence, matches argmax
    }
    atomicOr(&presT, 1u << am);
  }
  #pragma unroll
  for (int c = 0; c < NCLS; c++) atomicAdd(&csum[c], acc[c]);
  __syncthreads();
  if (tid == 0) {
    int cm = 0;
    for (int c = 0; c < NCLS; c++) {
      bool m = (cnt[c] > 0) && ((presT >> c) & 1u);
      if (m) cm++;
      wsf[WS_SVAL + c] = m ? 1.f / (float)cnt[c] : 0.f;
      float cs = csum[c]; if (cs == 0.f) cs = 100.f;
      wsf[WS_TVAL + c] = m ? -1.f / cs : 0.f;
    }
    wsf[WS_SVAL + 31] = 0.f; wsf[WS_TVAL + 31] = 0.f;  // pad column
    float scale = (cm > 0) ? 1.f / (float)cm : 0.f;
    float pp = (float)iter_p[0] / 1000.f;          // curr_iter / MAX_ITER
    float lamb = 2.f / (1.f + __expf(-pp)) - 1.f;  // GAMMA = 1
    wsf[WS_SL] = scale * lamb;
  }
}

__global__ void k_bw(float* __restrict__ wsf) {
  int tid = threadIdx.x;
  float c1 = wsf[WS_COL + tid], c2 = wsf[WS_COL + tid + 256];
  float v = c1*c1 + c2*c2;
  #pragma unroll
  for (int off = 32; off; off >>= 1) v += __shfl_down(v, off);
  __shared__ float part[4];
  if ((tid & 63) == 0) part[tid >> 6] = v;
  __syncthreads();
  if (tid == 0) {
    double colnorm2 = (double)part[0] + part[1] + part[2] + part[3];
    double sumsq = (double)wsf[WS_SUMSQ];
    // sum(L2) analytic: clamp only matters on the exactly-zero diagonal -> negligible
    double sumL2 = 2.0 * (double)N * sumsq - 2.0 * colnorm2;
    double bw = sumL2 / ((double)N * (double)N - (double)N) / 4.0; // / KERNEL_MUL^(5/2)=4
    #pragma unroll
    for (int k = 0; k < 5; k++)
      wsf[WS_NB + k] = (float)(-1.0 / (bw * (double)(1 << k)));
  }
}

// loss = scale*lamb * sum_{i,j} K_ij * (q_i . q_j)
__launch_bounds__(256, 4)
__global__ void k_main(const float* __restrict__ src, const float* __restrict__ tgt,
                       const int* __restrict__ label, const float* __restrict__ logits,
                       float* __restrict__ wsf) {
  __shared__ __align__(16) float lds[2 * BK * BT];  // A-tile/B-tile, later QiT/QjT
  __shared__ float sqi[BT], sqj[BT];
  __shared__ float red[4];
  const int tid = threadIdx.x;
  const int i0 = blockIdx.y * BT, j0 = blockIdx.x * BT;
  if (tid < 128) sqi[tid] = wsf[WS_SQ + i0 + tid];
  else           sqj[tid - 128] = wsf[WS_SQ + j0 + (tid - 128)];
  const float nb0 = wsf[WS_NB+0], nb1 = wsf[WS_NB+1], nb2 = wsf[WS_NB+2],
              nb3 = wsf[WS_NB+3], nb4 = wsf[WS_NB+4];
  const int tx = tid & 15, ty = tid >> 4;
  float dot[8][8];
  #pragma unroll
  for (int u = 0; u < 8; u++)
    #pragma unroll
    for (int v = 0; v < 8; v++) dot[u][v] = 0.f;

  const int f  = tid & 7;   // float4 index within 32-float K-chunk
  const int r0 = tid >> 3;  // 0..31
  for (int ko = 0; ko < D; ko += BK) {
    __syncthreads();
    #pragma unroll
    for (int p = 0; p < 4; p++) {
      int r = r0 + p * 32;
      int gi = i0 + r;
      const float* rp = (gi < B) ? src + (size_t)gi * D : tgt + (size_t)(gi - B) * D;
      float4 va = ((const float4*)(rp + ko))[f];
      lds[(f*4+0)*BT + r] = va.x;
      lds[(f*4+1)*BT + r] = va.y;
      lds[(f*4+2)*BT + r] = va.z;
      lds[(f*4+3)*BT + r] = va.w;
      int gj = j0 + r;
      const float* rq = (gj < B) ? src + (size_t)gj * D : tgt + (size_t)(gj - B) * D;
      float4 vb = ((const float4*)(rq + ko))[f];
      lds[BK*BT + (f*4+0)*BT + r] = vb.x;
      lds[BK*BT + (f*4+1)*BT + r] = vb.y;
      lds[BK*BT + (f*4+2)*BT + r] = vb.z;
      lds[BK*BT + (f*4+3)*BT + r] = vb.w;
    }
    __syncthreads();
    #pragma unroll 8
    for (int k = 0; k < BK; k++) {
      const float4* ap = (const float4*)&lds[k*BT + ty*8];
      const float4* bp = (const float4*)&lds[BK*BT + k*BT + tx*8];
      float4 a0 = ap[0], a1 = ap[1];
      float4 b0 = bp[0], b1 = bp[1];
      float a[8] = {a0.x,a0.y,a0.z,a0.w,a1.x,a1.y,a1.z,a1.w};
      float b[8] = {b0.x,b0.y,b0.z,b0.w,b1.x,b1.y,b1.z,b1.w};
      #pragma unroll
      for (int u = 0; u < 8; u++)
        #pragma unroll
        for (int v = 0; v < 8; v++)
          dot[u][v] = fmaf(a[u], b[v], dot[u][v]);
    }
  }
  // dot -> multi-scale Gaussian kernel value (in place)
  float si[8], sj[8];
  #pragma unroll
  for (int u = 0; u < 8; u++) { si[u] = sqi[ty*8+u]; sj[u] = sqj[tx*8+u]; }
  #pragma unroll
  for (int u = 0; u < 8; u++)
    #pragma unroll
    for (int v = 0; v < 8; v++) {
      float d2 = fmaxf(si[u] + sj[v] - 2.f * dot[u][v], 0.f);
      dot[u][v] = __expf(d2*nb0) + __expf(d2*nb1) + __expf(d2*nb2)
                + __expf(d2*nb3) + __expf(d2*nb4);
    }
  // build Q^T tiles (32 x 128, class-major) into reused LDS
  __syncthreads();
  {
    int t = tid & 127;
    float* qb = (tid < 128) ? lds : (lds + BK*BT);
    int gi = ((tid < 128) ? i0 : j0) + t;
    if (gi < B) {
      int c = label[gi];
      #pragma unroll
      for (int cc = 0; cc < 32; cc++) qb[cc*BT + t] = 0.f;
      qb[c*BT + t] = wsf[WS_SVAL + c];
    } else {
      const float* lp = logits + (size_t)(gi - B) * NCLS;
      for (int cc = 0; cc < NCLS; cc++) qb[cc*BT + t] = lp[cc] * wsf[WS_TVAL + cc];
      qb[31*BT + t] = 0.f;
    }
  }
  __syncthreads();
  float acc = 0.f;
  for (int c = 0; c < 32; c++) {
    const float4* qip = (const float4*)&lds[c*BT + ty*8];
    const float4* qjp = (const float4*)&lds[BK*BT + c*BT + tx*8];
    float4 qi0 = qip[0], qi1 = qip[1], qj0 = qjp[0], qj1 = qjp[1];
    float qi[8] = {qi0.x,qi0.y,qi0.z,qi0.w,qi1.x,qi1.y,qi1.z,qi1.w};
    float qj[8] = {qj0.x,qj0.y,qj0.z,qj0.w,qj1.x,qj1.y,qj1.z,qj1.w};
    #pragma unroll
    for (int u = 0; u < 8; u++) {
      float t = 0.f;
      #pragma unroll
      for (int v = 0; v < 8; v++) t = fmaf(dot[u][v], qj[v], t);
      acc = fmaf(qi[u], t, acc);
    }
  }
  #pragma unroll
  for (int off = 32; off; off >>= 1) acc += __shfl_down(acc, off);
  if ((tid & 63) == 0) red[tid >> 6] = acc;
  __syncthreads();
  if (tid == 0) atomicAdd(&wsf[WS_ACC], red[0] + red[1] + red[2] + red[3]);
}

__global__ void k_final(const float* __restrict__ wsf, float* __restrict__ out) {
  out[0] = wsf[WS_ACC] * wsf[WS_SL];
}

extern "C" void kernel_launch(void* const* d_in, const int* in_sizes, int n_in,
                              void* d_out, int out_size, void* d_ws, size_t ws_size,
                              hipStream_t stream) {
  const float* src    = (const float*)d_in[0];
  const float* tgt    = (const float*)d_in[1];
  const int*   label  = (const int*)d_in[2];
  const float* logits = (const float*)d_in[3];
  const int*   iter_p = (const int*)d_in[4];
  float* wsf = (float*)d_ws;
  float* out = (float*)d_out;

  hipMemsetAsync(d_ws, 0, 4096, stream);  // zero scalar/colsum accumulator region
  k_sq<<<N/4, 256, 0, stream>>>(src, tgt, wsf);
  k_colsum<<<dim3(2, 32), 256, 0, stream>>>(src, tgt, wsf);
  k_classes<<<1, 256, 0, stream>>>(label, logits, iter_p, wsf);
  k_bw<<<1, 256, 0, stream>>>(wsf);
  k_main<<<dim3(N/BT, N/BT), 256, 0, stream>>>(src, tgt, label, logits, wsf);
  k_final<<<1, 1, 0, stream>>>(wsf, out);
}

// Round 2
// 465.810 us; speedup vs baseline: 3.7305x; 3.7305x over previous
//
#include <hip/hip_runtime.h>
#include <math.h>

#define NCLS 31
#define B 4096
#define D 512
#define N 8192
#define BT 128
#define NT (N / BT)          // 64 tiles per dim
#define NBLK (NT * (NT + 1) / 2)  // 2080 upper-tri blocks
#define KB 1536              // effective GEMM K (hi|lo|hi vs hi|hi|lo)
#define BKB 64               // bf16 K-chunk per iteration
#define NITER (KB / BKB)     // 24

// ws float layout (header)
#define WS_SUMSQ 0
#define WS_ACC   1
#define WS_NBT   2           // -1/(16*b') = -(n^2-n)/(4*sumL2)
#define WS_SL    7           // scale * lamb
#define WS_SVAL  8           // 32: source class value m_c/count_c
#define WS_TVAL  40          // 32: target class value -m_c/colsum_c
#define WS_COL   72          // 512: column sums
#define WS_SQ    1024        // 8192: row squared norms
#define WS_XC_BYTES 65536    // byte offset of Xc (bf16 [8192][1024], 16 MB)

typedef __attribute__((ext_vector_type(8))) short bf16x8;
typedef __attribute__((ext_vector_type(4))) float f32x4;
typedef __attribute__((ext_vector_type(8))) unsigned short u16x8;

__device__ __forceinline__ unsigned short f2bf(float x) {
  unsigned u = __float_as_uint(x);
  u += 0x7fffu + ((u >> 16) & 1u);     // RNE (inputs finite)
  return (unsigned short)(u >> 16);
}
__device__ __forceinline__ float bf2f(unsigned short b) {
  return __uint_as_float(((unsigned)b) << 16);
}

__device__ __forceinline__ void async_lds16(const unsigned short* g, const short* l) {
  __builtin_amdgcn_global_load_lds(
      (const __attribute__((address_space(1))) unsigned int*)g,
      (__attribute__((address_space(3))) unsigned int*)l, 16, 0, 0);
}

// XOR-swizzled fragment read: logical (row r, 8-elem granule g) -> 16B
__device__ __forceinline__ bf16x8 frag_read(const short* tile, int r, int g) {
  int phys = r * 8 + (g ^ (r & 7));
  return *(const bf16x8*)(tile + phys * 8);
}

__global__ void k_cvt(const float* __restrict__ src, const float* __restrict__ tgt,
                      unsigned short* __restrict__ Xc) {
  int idx = blockIdx.x * 256 + threadIdx.x;   // float4 index
  int off = idx * 4;
  int row = off >> 9, col = off & 511;
  const float* p = (row < B) ? src + (size_t)row * D + col
                             : tgt + (size_t)(row - B) * D + col;
  float4 v = *(const float4*)p;
  ushort4 h, l;
  h.x = f2bf(v.x); l.x = f2bf(v.x - bf2f(h.x));
  h.y = f2bf(v.y); l.y = f2bf(v.y - bf2f(h.y));
  h.z = f2bf(v.z); l.z = f2bf(v.z - bf2f(h.z));
  h.w = f2bf(v.w); l.w = f2bf(v.w - bf2f(h.w));
  *(ushort4*)(Xc + (size_t)row * 1024 + col) = h;
  *(ushort4*)(Xc + (size_t)row * 1024 + 512 + col) = l;
}

__global__ void k_sq(const float* __restrict__ src, const float* __restrict__ tgt,
                     float* __restrict__ wsf) {
  int row = blockIdx.x * 4 + (threadIdx.x >> 6);
  int lane = threadIdx.x & 63;
  const float* p = (row < B) ? src + (size_t)row * D : tgt + (size_t)(row - B) * D;
  const float4* p4 = (const float4*)p;
  float4 a = p4[lane], b = p4[lane + 64];
  float s = a.x*a.x + a.y*a.y + a.z*a.z + a.w*a.w
          + b.x*b.x + b.y*b.y + b.z*b.z + b.w*b.w;
  #pragma unroll
  for (int off = 32; off; off >>= 1) s += __shfl_down(s, off);
  if (lane == 0) {
    wsf[WS_SQ + row] = s;
    atomicAdd(&wsf[WS_SUMSQ], s);
  }
}

__global__ void k_colsum(const float* __restrict__ src, const float* __restrict__ tgt,
                         float* __restrict__ wsf) {
  int d = blockIdx.x * 256 + threadIdx.x;
  int r0 = blockIdx.y * 256;
  const float* base = (r0 < B) ? src + (size_t)r0 * D : tgt + (size_t)(r0 - B) * D;
  float s = 0.f;
  for (int r = 0; r < 256; r++) s += base[(size_t)r * D + d];
  atomicAdd(&wsf[WS_COL + d], s);
}

__global__ void k_classes(const int* __restrict__ label, const float* __restrict__ logits,
                          const int* __restrict__ iter_p, float* __restrict__ wsf) {
  __shared__ int cnt[NCLS];
  __shared__ float csum[NCLS];
  __shared__ unsigned presT;
  int tid = threadIdx.x;
  if (tid < NCLS) { cnt[tid] = 0; csum[tid] = 0.f; }
  if (tid == 0) presT = 0u;
  __syncthreads();
  float acc[NCLS];
  #pragma unroll
  for (int c = 0; c < NCLS; c++) acc[c] = 0.f;
  for (int r = tid; r < B; r += 256) {
    atomicAdd(&cnt[label[r]], 1);
    const float* lp = logits + (size_t)r * NCLS;
    float mx = -1e30f; int am = 0;
    #pragma unroll
    for (int c = 0; c < NCLS; c++) {
      float v = lp[c];
      acc[c] += v;
      if (v > mx) { mx = v; am = c; }
    }
    atomicOr(&presT, 1u << am);
  }
  #pragma unroll
  for (int c = 0; c < NCLS; c++) atomicAdd(&csum[c], acc[c]);
  __syncthreads();
  if (tid == 0) {
    int cm = 0;
    for (int c = 0; c < NCLS; c++) {
      bool m = (cnt[c] > 0) && ((presT >> c) & 1u);
      if (m) cm++;
      wsf[WS_SVAL + c] = m ? 1.f / (float)cnt[c] : 0.f;
      float cs = csum[c]; if (cs == 0.f) cs = 100.f;
      wsf[WS_TVAL + c] = m ? -1.f / cs : 0.f;
    }
    wsf[WS_SVAL + 31] = 0.f; wsf[WS_TVAL + 31] = 0.f;
    float scale = (cm > 0) ? 1.f / (float)cm : 0.f;
    float pp = (float)iter_p[0] / 1000.f;
    float lamb = 2.f / (1.f + __expf(-pp)) - 1.f;
    wsf[WS_SL] = scale * lamb;
  }
}

__global__ void k_bw(float* __restrict__ wsf) {
  int tid = threadIdx.x;
  float c1 = wsf[WS_COL + tid], c2 = wsf[WS_COL + tid + 256];
  float v = c1*c1 + c2*c2;
  #pragma unroll
  for (int off = 32; off; off >>= 1) v += __shfl_down(v, off);
  __shared__ float part[4];
  if ((tid & 63) == 0) part[tid >> 6] = v;
  __syncthreads();
  if (tid == 0) {
    double colnorm2 = (double)part[0] + part[1] + part[2] + part[3];
    double sumsq = (double)wsf[WS_SUMSQ];
    double sumL2 = 2.0 * (double)N * sumsq - 2.0 * colnorm2;
    // b' = sumL2/(n^2-n)/4; largest band = 16*b'; nbt = -1/(16 b')
    wsf[WS_NBT] = (float)(-((double)N * (double)N - (double)N) / (4.0 * sumL2));
  }
}

// loss_part = sum_{i,j in tile} K(d2_ij) * (q_i . q_j), via bf16 MFMA hi/lo GEMMs
__launch_bounds__(256, 3)
__global__ void k_main(const unsigned short* __restrict__ Xc,
                       const int* __restrict__ label, const float* __restrict__ logits,
                       float* __restrict__ wsf) {
  __shared__ __align__(16) short tileA[BT * BKB];   // 16 KB, XOR-swizzled
  __shared__ __align__(16) short tileB[BT * BKB];   // 16 KB
  __shared__ float sqi[BT], sqj[BT];
  __shared__ float red[4];

  // triangular block decode: bi <= bj, S(r) = r*(129-r)/2
  int bid = blockIdx.x;
  int bi = (int)(64.5f - sqrtf(64.5f * 64.5f - 2.0f * (float)bid));
  while (bi > 0 && bid < (bi * (129 - bi)) / 2) --bi;
  while (bid >= ((bi + 1) * (128 - bi)) / 2) ++bi;   // S(bi+1) = (bi+1)*(129-bi-1)/2
  int bj = bi + (bid - (bi * (129 - bi)) / 2);
  const int i0 = bi * BT, j0 = bj * BT;
  const float mult = (bi == bj) ? 1.f : 2.f;

  const int tid = threadIdx.x;
  const int w = tid >> 6, lane = tid & 63;
  const int woff_m = (w >> 1) * 64, woff_n = (w & 1) * 64;
  const int fr = lane & 15, fg = lane >> 4;       // fragment row / k-group
  const int srow = lane >> 3;                     // staging row-in-8
  const int sgrp = (lane & 7) ^ srow;             // staging logical granule

  if (tid < 128) sqi[tid] = wsf[WS_SQ + i0 + tid];
  else           sqj[tid - 128] = wsf[WS_SQ + j0 + (tid - 128)];
  const float nbt = wsf[WS_NBT];

  f32x4 acc[4][4];
  #pragma unroll
  for (int mt = 0; mt < 4; mt++)
    #pragma unroll
    for (int nt = 0; nt < 4; nt++) acc[mt][nt] = (f32x4){0.f, 0.f, 0.f, 0.f};

  for (int it = 0; it < NITER; ++it) {
    // segment remap: A' = [hi|lo|hi], B' = [hi|hi|lo] over Xc rows [hi(512)|lo(512)]
    const int offA = (it < 16 ? it : it - 16) * BKB;
    const int offB = (it < 8 ? it : it - 8) * BKB;
    __syncthreads();
    #pragma unroll
    for (int q = 0; q < 4; ++q) {
      const int inst = w * 4 + q;                  // 0..15, 8 rows each
      const int rl = inst * 8 + srow;              // local row 0..127
      async_lds16(Xc + (size_t)(i0 + rl) * 1024 + offA + sgrp * 8,
                  tileA + inst * 512);
      async_lds16(Xc + (size_t)(j0 + rl) * 1024 + offB + sgrp * 8,
                  tileB + inst * 512);
    }
    __syncthreads();
    #pragma unroll
    for (int ks = 0; ks < 2; ++ks) {
      bf16x8 af[4], bfr[4];
      #pragma unroll
      for (int mt = 0; mt < 4; mt++)
        af[mt] = frag_read(tileA, woff_m + mt * 16 + fr, ks * 4 + fg);
      #pragma unroll
      for (int nt = 0; nt < 4; nt++)
        bfr[nt] = frag_read(tileB, woff_n + nt * 16 + fr, ks * 4 + fg);
      #pragma unroll
      for (int mt = 0; mt < 4; mt++)
        #pragma unroll
        for (int nt = 0; nt < 4; nt++)
          acc[mt][nt] = __builtin_amdgcn_mfma_f32_16x16x32_bf16(
              af[mt], bfr[nt], acc[mt][nt], 0, 0, 0);
    }
  }

  // transform acc -> multi-band Gaussian kernel: t + t^2 + t^4 + t^8 + t^16
  float sj4[4], si16[4][4];
  #pragma unroll
  for (int nt = 0; nt < 4; nt++) sj4[nt] = sqj[woff_n + nt * 16 + fr];
  #pragma unroll
  for (int mt = 0; mt < 4; mt++)
    #pragma unroll
    for (int t = 0; t < 4; t++) si16[mt][t] = sqi[woff_m + mt * 16 + fg * 4 + t];
  #pragma unroll
  for (int mt = 0; mt < 4; mt++)
    #pragma unroll
    for (int nt = 0; nt < 4; nt++)
      #pragma unroll
      for (int t = 0; t < 4; t++) {
        float d2 = fmaxf(si16[mt][t] + sj4[nt] - 2.f * acc[mt][nt][t], 0.f);
        float e1 = __expf(d2 * nbt);
        float e2 = e1 * e1, e4 = e2 * e2, e8 = e4 * e4, e16 = e8 * e8;
        acc[mt][nt][t] = ((e16 + e8) + (e4 + e2)) + e1;
      }

  // build Q tiles (hi|lo bf16, rows 0..127) into reused LDS, same swizzle
  __syncthreads();
  {
    const int t = tid & 127;
    short* qt = (tid < 128) ? tileA : tileB;
    const int gq = ((tid < 128) ? i0 : j0) + t;
    const int lab = (gq < B) ? label[gq] : -1;
    const float sv = (gq < B) ? wsf[WS_SVAL + lab] : 0.f;
    const float* lp = (gq < B) ? (const float*)0 : logits + (size_t)(gq - B) * NCLS;
    #pragma unroll
    for (int g = 0; g < 8; ++g) {
      u16x8 pack = (u16x8){0,0,0,0,0,0,0,0};
      const int cbase = (g & 3) * 8;
      if (gq < B) {
        if (lab >= cbase && lab < cbase + 8) {
          unsigned short h = f2bf(sv);
          pack[lab - cbase] = (g < 4) ? h : f2bf(sv - bf2f(h));
        }
      } else {
        #pragma unroll
        for (int jc = 0; jc < 8; ++jc) {
          int cc = cbase + jc;
          if (cc < NCLS) {
            float v = lp[cc] * wsf[WS_TVAL + cc];
            unsigned short h = f2bf(v);
            pack[jc] = (g < 4) ? h : f2bf(v - bf2f(h));
          }
        }
      }
      int phys = t * 8 + (g ^ (t & 7));
      *(u16x8*)(qt + phys * 8) = pack;
    }
  }
  __syncthreads();

  // Gram via MFMA (K=96: hi.hi + lo.hi + hi.lo), elementwise-dot with K values
  float part = 0.f;
  #pragma unroll
  for (int ch = 0; ch < 3; ++ch) {
    const int ab = (ch == 1) ? 4 : 0, bb = (ch == 2) ? 4 : 0;
    bf16x8 af[4], bfr[4];
    #pragma unroll
    for (int mt = 0; mt < 4; mt++)
      af[mt] = frag_read(tileA, woff_m + mt * 16 + fr, ab + fg);
    #pragma unroll
    for (int nt = 0; nt < 4; nt++)
      bfr[nt] = frag_read(tileB, woff_n + nt * 16 + fr, bb + fg);
    #pragma unroll
    for (int mt = 0; mt < 4; mt++)
      #pragma unroll
      for (int nt = 0; nt < 4; nt++) {
        f32x4 z = (f32x4){0.f, 0.f, 0.f, 0.f};
        f32x4 g = __builtin_amdgcn_mfma_f32_16x16x32_bf16(af[mt], bfr[nt], z, 0, 0, 0);
        part += acc[mt][nt].x * g.x + acc[mt][nt].y * g.y
              + acc[mt][nt].z * g.z + acc[mt][nt].w * g.w;
      }
  }
  part *= mult;
  #pragma unroll
  for (int off = 32; off; off >>= 1) part += __shfl_down(part, off);
  if (lane == 0) red[w] = part;
  __syncthreads();
  if (tid == 0) atomicAdd(&wsf[WS_ACC], red[0] + red[1] + red[2] + red[3]);
}

__global__ void k_final(const float* __restrict__ wsf, float* __restrict__ out) {
  out[0] = wsf[WS_ACC] * wsf[WS_SL];
}

extern "C" void kernel_launch(void* const* d_in, const int* in_sizes, int n_in,
                              void* d_out, int out_size, void* d_ws, size_t ws_size,
                              hipStream_t stream) {
  const float* src    = (const float*)d_in[0];
  const float* tgt    = (const float*)d_in[1];
  const int*   label  = (const int*)d_in[2];
  const float* logits = (const float*)d_in[3];
  const int*   iter_p = (const int*)d_in[4];
  float* wsf = (float*)d_ws;
  unsigned short* Xc = (unsigned short*)((char*)d_ws + WS_XC_BYTES);
  float* out = (float*)d_out;

  hipMemsetAsync(d_ws, 0, 4096, stream);
  k_cvt<<<(N * D / 4) / 256, 256, 0, stream>>>(src, tgt, Xc);
  k_sq<<<N / 4, 256, 0, stream>>>(src, tgt, wsf);
  k_colsum<<<dim3(2, 32), 256, 0, stream>>>(src, tgt, wsf);
  k_classes<<<1, 256, 0, stream>>>(label, logits, iter_p, wsf);
  k_bw<<<1, 256, 0, stream>>>(wsf);
  k_main<<<NBLK, 256, 0, stream>>>(Xc, label, logits, wsf);
  k_final<<<1, 1, 0, stream>>>(wsf, out);
}